// Round 1
// baseline (856.651 us; speedup 1.0000x reference)
//
#include <hip/hip_runtime.h>

#define B_ 2
#define S_ 2048
#define D_ 1024      // D_IN = DKQ = DV = E
#define H_ 16
#define HD_ 64       // DV / H

typedef _Float16 f16;
typedef _Float16 half8 __attribute__((ext_vector_type(8)));
typedef float float4_ __attribute__((ext_vector_type(4)));

#define N_HS (B_*S_*D_)   // 4194304
#define N_W  (D_*D_)      // 1048576
#define N_MIX (H_*D_)     // 16384

__device__ __forceinline__ void gl_lds16(const f16* g, const f16* l) {
  __builtin_amdgcn_global_load_lds(
      (const __attribute__((address_space(1))) void*)g,
      (__attribute__((address_space(3))) void*)l, 16, 0, 0);
}

// ---------------- convert fp32 -> fp16 ----------------
// mixing scaled by (1/sqrt(64)) * (1/ln2): softmax exp becomes a bare exp2
#define MIX_SCALE 0.18033688011112042f

__global__ __launch_bounds__(256) void convert_kernel(
    const float* __restrict__ hs, const float* __restrict__ wq,
    const float* __restrict__ wk, const float* __restrict__ wv,
    const float* __restrict__ mix,
    f16* __restrict__ hs16, f16* __restrict__ wq16, f16* __restrict__ wk16,
    f16* __restrict__ wv16, f16* __restrict__ mix16)
{
  const int total4 = (N_HS + 3*N_W + N_MIX) / 4;
  for (int i4 = blockIdx.x*blockDim.x + threadIdx.x; i4 < total4;
       i4 += gridDim.x*blockDim.x) {
    int i = i4*4;
    const float* src; f16* dst; float scale = 1.0f; int off;
    if (i < N_HS)            { src=hs;  dst=hs16;  off=i; }
    else if (i < N_HS+N_W)   { src=wq;  dst=wq16;  off=i-N_HS; }
    else if (i < N_HS+2*N_W) { src=wk;  dst=wk16;  off=i-N_HS-N_W; }
    else if (i < N_HS+3*N_W) { src=wv;  dst=wv16;  off=i-N_HS-2*N_W; }
    else                     { src=mix; dst=mix16; off=i-N_HS-3*N_W; scale=MIX_SCALE; }
    float4 v = *(const float4*)(src+off);
    dst[off]   = (f16)(v.x*scale);
    dst[off+1] = (f16)(v.y*scale);
    dst[off+2] = (f16)(v.z*scale);
    dst[off+3] = (f16)(v.w*scale);
  }
}

// ---------------- QKV GEMM: 128x128 tiles, DMA staging (m97-style) ----------------
// z==2 (V) adds bias and writes TRANSPOSED: vT[b][ch][t]
#define BM 128
#define BN 128
#define BK 64

__global__ __launch_bounds__(256, 2) void qkv_kernel(
    const f16* __restrict__ hs16, const f16* __restrict__ w16base,
    const float* __restrict__ bv,
    f16* __restrict__ q16, f16* __restrict__ k16, f16* __restrict__ vT)
{
  const int z = blockIdx.z;
  const f16* W = w16base + (size_t)z * N_W;
  f16* out = (z==0) ? q16 : k16;
  const int mt = blockIdx.y, nt = blockIdx.x;
  const int tid = threadIdx.x;
  const int lane = tid & 63, wid = tid >> 6;
  const int wm = wid >> 1, wn = wid & 1;
  const int quad = lane >> 4, l16 = lane & 15;

  // unpadded, xor-swizzled chunk layout (same scheme as attn k-tiles)
  __shared__ __align__(16) f16 As[BM*BK];   // 16 KB
  __shared__ __align__(16) f16 Bs[BN*BK];   // 16 KB

  float4_ acc[4][4];
#pragma unroll
  for (int i=0;i<4;i++)
#pragma unroll
    for (int j=0;j<4;j++) acc[i][j] = (float4_)0.0f;

  const int row0 = mt*BM;
  const int col0 = nt*BN;

  for (int ko = 0; ko < D_; ko += BK) {
#pragma unroll
    for (int c=0; c<4; c++) {
      int slot = (wid*4+c)*64 + lane;      // 0..1023 16B chunks
      int r = slot >> 3;
      int gc = (slot & 7) ^ (r & 7);
      gl_lds16(hs16 + (size_t)(row0+r)*D_ + ko + gc*8, As + (size_t)(wid*4+c)*64*8);
      gl_lds16(W    + (size_t)(col0+r)*D_ + ko + gc*8, Bs + (size_t)(wid*4+c)*64*8);
    }
    __syncthreads();
#pragma unroll
    for (int kk=0; kk<BK; kk+=32) {
      int ck = (kk >> 3) + quad;
      half8 a[4], b[4];
#pragma unroll
      for (int i=0;i<4;i++) {
        int rr = wm*64 + i*16 + l16;
        a[i] = *(const half8*)&As[(size_t)(((rr<<3) | (ck ^ (rr&7))) << 3)];
      }
#pragma unroll
      for (int j=0;j<4;j++) {
        int rr = wn*64 + j*16 + l16;
        b[j] = *(const half8*)&Bs[(size_t)(((rr<<3) | (ck ^ (rr&7))) << 3)];
      }
#pragma unroll
      for (int i=0;i<4;i++)
#pragma unroll
        for (int j=0;j<4;j++)
          acc[i][j] = __builtin_amdgcn_mfma_f32_16x16x32_f16(a[i], b[j], acc[i][j], 0,0,0);
    }
    __syncthreads();
  }
#pragma unroll
  for (int i=0;i<4;i++) {
#pragma unroll
    for (int j=0;j<4;j++) {
      int colg = col0 + wn*64 + j*16 + l16;
      float bias = (z==2) ? bv[colg] : 0.0f;
#pragma unroll
      for (int r=0;r<4;r++) {
        int rowg = row0 + wm*64 + i*16 + quad*4 + r;
        f16 val = (f16)(acc[i][j][r] + bias);
        if (z == 2) {
          int bb = rowg >> 11, ss = rowg & (S_-1);
          vT[((size_t)bb*D_ + colg)*S_ + ss] = val;
        } else {
          out[(size_t)rowg*D_ + colg] = val;
        }
      }
    }
  }
}

// ---------------- flash attention (pipelined rewrite) ----------------
// Changes vs previous round:
//  * k-tile pair DOUBLE-BUFFERED in LDS (4x16KB); DMA for the next ko issued
//    AFTER the barrier into the idle pair -> the barrier's implicit vmcnt(0)
//    drains loads that completed under the previous MFMA phase (free), and
//    this ko's DMA overlaps this ko's MFMAs.  ONE barrier per ko (was two).
//  * q-LDS staging eliminated: A-fragments loaded straight from global
//    (coalesced 16 rows x 64B, L1/L2/L3-resident) and multiplied by the mix
//    chunk in registers.  Removes the q-write barrier + staging VALU/LDS ops.
//  * P (34816 B) aliases the k-buffer region via union; next t0's first DMA
//    issues after the final PV barrier of the current t0.
//  * s_setprio(1) around MFMA clusters (blocks run at different phases).
#define TQ 128
#define TK 128
#define LDP 136

__global__ __launch_bounds__(256, 2) void attn_kernel(
    const f16* __restrict__ q16, const f16* __restrict__ k16,
    const f16* __restrict__ vT, const f16* __restrict__ mix16,
    float* __restrict__ out)
{
  const int b = blockIdx.z;
  const int h = blockIdx.y;
  const int s0 = blockIdx.x * TQ;
  const int tid = threadIdx.x;
  const int lane = tid & 63, wid = tid >> 6;
  const int wm = wid >> 1, wn = wid & 1;
  const int quad = lane >> 4, l16 = lane & 15;

  // two ping-pong k-tile PAIRS: {k[0],k[1]} (even ko) / {k[2],k[3]} (odd ko)
  __shared__ __align__(16) union {
    f16 k[4][TK*BK];   // 65536 B
    f16 P[TQ][LDP];    // 34816 B (aliases pair0 + first 2KB of k[2])
  } u;
  __shared__ __align__(16) float red_l[2][TQ];   // 1024 B

  float l_lane[16];
#pragma unroll
  for (int t=0;t<16;t++) l_lane[t] = 0.0f;

  float4_ o_acc[4][2];
#pragma unroll
  for (int i=0;i<4;i++)
#pragma unroll
    for (int j=0;j<2;j++) o_acc[i][j] = (float4_)0.0f;

  const f16* qbase = q16 + (size_t)(b*S_ + s0)*D_;
  const f16* kbase = k16 + (size_t)b*S_*D_;
  const f16* mrow  = mix16 + h*D_;
  const f16* vTb   = vT + (size_t)(b*D_ + h*HD_)*S_;

  // stage k-tile pair p (tiles u.k[2p], u.k[2p+1]) for (t0g, ko_): 8 DMA/thread
#define STAGE_PAIR(p, t0g, ko_) do {                                         \
    const f16* k0g_ = kbase + (size_t)(t0g)*D_ + (ko_);                      \
    const f16* k1g_ = k0g_ + (size_t)TK*D_;                                  \
    _Pragma("unroll")                                                        \
    for (int c_=0; c_<4; c_++) {                                             \
      int slot_ = (wid*4+c_)*64 + lane;                                      \
      int r_ = slot_ >> 3;                                                   \
      int gc_ = (slot_ & 7) ^ (r_ & 7);                                      \
      gl_lds16(k0g_ + (size_t)r_*D_ + gc_*8, u.k[2*(p)]   + (size_t)(wid*4+c_)*64*8); \
      gl_lds16(k1g_ + (size_t)r_*D_ + gc_*8, u.k[2*(p)+1] + (size_t)(wid*4+c_)*64*8); \
    } } while (0)

  STAGE_PAIR(0, 0, 0);   // prologue for t0=0

  for (int t0 = 0; t0 < S_; t0 += 2*TK) {
    // ---- S[2 tiles] = (q*mix) @ k^T over K=1024, single barrier per ko ----
    float4_ sacc[2][4][4];
#pragma unroll
    for (int tt=0;tt<2;tt++)
#pragma unroll
      for (int i=0;i<4;i++)
#pragma unroll
        for (int j=0;j<4;j++) sacc[tt][i][j] = (float4_)0.0f;

#pragma unroll 2
    for (int ko_i = 0; ko_i < D_/BK; ko_i++) {
      const int ko = ko_i * BK;
      const int cur = ko_i & 1;
      // drains DMA(pair cur) issued one full MFMA phase ago (already complete)
      __syncthreads();
      // prefetch next ko's pair into the buffer everyone just finished reading
      if (ko_i < D_/BK - 1) STAGE_PAIR(cur^1, t0, ko + BK);

      __builtin_amdgcn_s_setprio(1);
#pragma unroll
      for (int kk2=0; kk2<2; kk2++) {
        const int kc = ko + kk2*32 + quad*8;
        half8 mv = *(const half8*)&mrow[kc];
        half8 a[4];
#pragma unroll
        for (int i=0;i<4;i++)
          a[i] = *(const half8*)&qbase[(size_t)(wm*64 + i*16 + l16)*D_ + kc] * mv;
#pragma unroll
        for (int tt=0;tt<2;tt++) {
          const f16* kb = u.k[2*cur + tt];
          half8 bf[4];
#pragma unroll
          for (int j=0;j<4;j++) {
            int rr = wn*64 + j*16 + l16;
            int ck = kk2*4 + quad;
            bf[j] = *(const half8*)&kb[(size_t)(((rr<<3) | (ck ^ (rr&7))) << 3)];
          }
#pragma unroll
          for (int i=0;i<4;i++)
#pragma unroll
            for (int j=0;j<4;j++)
              sacc[tt][i][j] = __builtin_amdgcn_mfma_f32_16x16x32_f16(a[i], bf[j], sacc[tt][i][j], 0,0,0);
        }
      }
      __builtin_amdgcn_s_setprio(0);
    }
    // all k ds_reads done before P overwrites the aliased region
    __syncthreads();

    // ---- per sub-tile: P = exp2(S), l partials, P->LDS, PV ----
#pragma unroll
    for (int tt=0;tt<2;tt++) {
#pragma unroll
      for (int i=0;i<4;i++)
#pragma unroll
        for (int j=0;j<4;j++)
#pragma unroll
          for (int r=0;r<4;r++) {
            float p = __builtin_exp2f(sacc[tt][i][j][r]);
            l_lane[i*4+r] += p;
            u.P[wm*64+i*16+quad*4+r][wn*64+j*16+l16] = (f16)p;
          }

      // prefetch PV B-fragments (latency hides under barrier)
      half8 vb[8];
#pragma unroll
      for (int ki=0; ki<4; ki++)
#pragma unroll
        for (int j=0; j<2; j++) {
          int ch = wn*32 + j*16 + l16;
          vb[ki*2+j] = *(const half8*)&vTb[(size_t)ch*S_ + t0 + tt*TK + ki*32 + quad*8];
        }

      __syncthreads();

      __builtin_amdgcn_s_setprio(1);
#pragma unroll
      for (int ki=0; ki<4; ki++) {
        half8 pa[4];
#pragma unroll
        for (int i=0;i<4;i++) pa[i] = *(const half8*)&u.P[wm*64+i*16+l16][ki*32+quad*8];
#pragma unroll
        for (int i=0;i<4;i++)
#pragma unroll
          for (int j=0;j<2;j++)
            o_acc[i][j] = __builtin_amdgcn_mfma_f32_16x16x32_f16(pa[i], vb[ki*2+j], o_acc[i][j], 0,0,0);
      }
      __builtin_amdgcn_s_setprio(0);
      __syncthreads();
    }

    // prologue DMA for the next t0 (pair0 region now dead: P reads complete)
    if (t0 + 2*TK < S_) STAGE_PAIR(0, t0 + 2*TK, 0);
  }

  // ---- epilogue: single l reduction (butterfly over l16, cross-wave via LDS) ----
#pragma unroll
  for (int d=1; d<16; d<<=1)
#pragma unroll
    for (int t=0;t<16;t++) l_lane[t] += __shfl_xor(l_lane[t], d);
  if (l16 == 0) {
#pragma unroll
    for (int i=0;i<4;i++)
#pragma unroll
      for (int r=0;r<4;r++)
        red_l[wn][wm*64+i*16+quad*4+r] = l_lane[i*4+r];
  }
  __syncthreads();

#pragma unroll
  for (int i=0;i<4;i++) {
#pragma unroll
    for (int r=0;r<4;r++) {
      int row = wm*64 + i*16 + quad*4 + r;
      float linv = 1.0f / (red_l[0][row] + red_l[1][row]);
#pragma unroll
      for (int j=0;j<2;j++) {
        int colg = h*HD_ + wn*32 + j*16 + l16;
        out[(size_t)(b*S_ + s0 + row)*D_ + colg] = o_acc[i][j][r] * linv;
      }
    }
  }
}

// ---------------- launch ----------------
extern "C" void kernel_launch(void* const* d_in, const int* in_sizes, int n_in,
                              void* d_out, int out_size, void* d_ws, size_t ws_size,
                              hipStream_t stream) {
  (void)in_sizes; (void)n_in; (void)out_size; (void)ws_size;
  const float* hs  = (const float*)d_in[0];
  const float* Wq  = (const float*)d_in[1];
  const float* Wk  = (const float*)d_in[2];
  const float* Wv  = (const float*)d_in[3];
  const float* bv  = (const float*)d_in[4];
  const float* mix = (const float*)d_in[5];
  float* out = (float*)d_out;

  char* ws = (char*)d_ws;
  f16* hs16  = (f16*)(ws);                       // 8 MB
  f16* w16   = (f16*)(ws + 8388608);             // 6 MB
  f16* mix16 = (f16*)(ws + 14680064);            // 32 KB
  f16* q16   = (f16*)(ws + 14712832);            // 8 MB
  f16* k16   = (f16*)(ws + 23101440);            // 8 MB
  f16* vT    = (f16*)(ws + 31490048);            // 8 MB

  convert_kernel<<<2048, 256, 0, stream>>>(hs, Wq, Wk, Wv, mix,
                                           hs16, w16, w16+N_W, w16+2*N_W, mix16);
  qkv_kernel<<<dim3(D_/BN, (B_*S_)/BM, 3), 256, 0, stream>>>(
      hs16, w16, bv, q16, k16, vT);
  attn_kernel<<<dim3(S_/TQ, H_, B_), 256, 0, stream>>>(
      q16, k16, vT, mix16, out);
}

// Round 2
// 613.283 us; speedup vs baseline: 1.3968x; 1.3968x over previous
//
#include <hip/hip_runtime.h>

#define B_ 2
#define S_ 2048
#define D_ 1024      // D_IN = DKQ = DV = E
#define H_ 16
#define HD_ 64       // DV / H

typedef _Float16 f16;
typedef _Float16 half8 __attribute__((ext_vector_type(8)));
typedef float float4_ __attribute__((ext_vector_type(4)));

#define N_HS (B_*S_*D_)   // 4194304
#define N_W  (D_*D_)      // 1048576
#define N_MIX (H_*D_)     // 16384

__device__ __forceinline__ void gl_lds16(const f16* g, const f16* l) {
  __builtin_amdgcn_global_load_lds(
      (const __attribute__((address_space(1))) void*)g,
      (__attribute__((address_space(3))) void*)l, 16, 0, 0);
}

// ---------------- convert fp32 -> fp16 ----------------
// mixing scaled by (1/sqrt(64)) * (1/ln2): softmax exp becomes a bare exp2
#define MIX_SCALE 0.18033688011112042f

__global__ __launch_bounds__(256) void convert_kernel(
    const float* __restrict__ hs, const float* __restrict__ wq,
    const float* __restrict__ wk, const float* __restrict__ wv,
    const float* __restrict__ mix,
    f16* __restrict__ hs16, f16* __restrict__ wq16, f16* __restrict__ wk16,
    f16* __restrict__ wv16, f16* __restrict__ mix16)
{
  const int total4 = (N_HS + 3*N_W + N_MIX) / 4;
  for (int i4 = blockIdx.x*blockDim.x + threadIdx.x; i4 < total4;
       i4 += gridDim.x*blockDim.x) {
    int i = i4*4;
    const float* src; f16* dst; float scale = 1.0f; int off;
    if (i < N_HS)            { src=hs;  dst=hs16;  off=i; }
    else if (i < N_HS+N_W)   { src=wq;  dst=wq16;  off=i-N_HS; }
    else if (i < N_HS+2*N_W) { src=wk;  dst=wk16;  off=i-N_HS-N_W; }
    else if (i < N_HS+3*N_W) { src=wv;  dst=wv16;  off=i-N_HS-2*N_W; }
    else                     { src=mix; dst=mix16; off=i-N_HS-3*N_W; scale=MIX_SCALE; }
    float4 v = *(const float4*)(src+off);
    dst[off]   = (f16)(v.x*scale);
    dst[off+1] = (f16)(v.y*scale);
    dst[off+2] = (f16)(v.z*scale);
    dst[off+3] = (f16)(v.w*scale);
  }
}

// ---------------- QKV GEMM: 128x128 tiles, DMA staging (m97-style) ----------------
// z==2 (V) adds bias and writes TRANSPOSED: vT[b][ch][t]
#define BM 128
#define BN 128
#define BK 64

__global__ __launch_bounds__(256, 2) void qkv_kernel(
    const f16* __restrict__ hs16, const f16* __restrict__ w16base,
    const float* __restrict__ bv,
    f16* __restrict__ q16, f16* __restrict__ k16, f16* __restrict__ vT)
{
  const int z = blockIdx.z;
  const f16* W = w16base + (size_t)z * N_W;
  f16* out = (z==0) ? q16 : k16;
  const int mt = blockIdx.y, nt = blockIdx.x;
  const int tid = threadIdx.x;
  const int lane = tid & 63, wid = tid >> 6;
  const int wm = wid >> 1, wn = wid & 1;
  const int quad = lane >> 4, l16 = lane & 15;

  // unpadded, xor-swizzled chunk layout (same scheme as attn k-tiles)
  __shared__ __align__(16) f16 As[BM*BK];   // 16 KB
  __shared__ __align__(16) f16 Bs[BN*BK];   // 16 KB

  float4_ acc[4][4];
#pragma unroll
  for (int i=0;i<4;i++)
#pragma unroll
    for (int j=0;j<4;j++) acc[i][j] = (float4_)0.0f;

  const int row0 = mt*BM;
  const int col0 = nt*BN;

  for (int ko = 0; ko < D_; ko += BK) {
#pragma unroll
    for (int c=0; c<4; c++) {
      int slot = (wid*4+c)*64 + lane;      // 0..1023 16B chunks
      int r = slot >> 3;
      int gc = (slot & 7) ^ (r & 7);
      gl_lds16(hs16 + (size_t)(row0+r)*D_ + ko + gc*8, As + (size_t)(wid*4+c)*64*8);
      gl_lds16(W    + (size_t)(col0+r)*D_ + ko + gc*8, Bs + (size_t)(wid*4+c)*64*8);
    }
    __syncthreads();
#pragma unroll
    for (int kk=0; kk<BK; kk+=32) {
      int ck = (kk >> 3) + quad;
      half8 a[4], b[4];
#pragma unroll
      for (int i=0;i<4;i++) {
        int rr = wm*64 + i*16 + l16;
        a[i] = *(const half8*)&As[(size_t)(((rr<<3) | (ck ^ (rr&7))) << 3)];
      }
#pragma unroll
      for (int j=0;j<4;j++) {
        int rr = wn*64 + j*16 + l16;
        b[j] = *(const half8*)&Bs[(size_t)(((rr<<3) | (ck ^ (rr&7))) << 3)];
      }
#pragma unroll
      for (int i=0;i<4;i++)
#pragma unroll
        for (int j=0;j<4;j++)
          acc[i][j] = __builtin_amdgcn_mfma_f32_16x16x32_f16(a[i], b[j], acc[i][j], 0,0,0);
    }
    __syncthreads();
  }
#pragma unroll
  for (int i=0;i<4;i++) {
#pragma unroll
    for (int j=0;j<4;j++) {
      int colg = col0 + wn*64 + j*16 + l16;
      float bias = (z==2) ? bv[colg] : 0.0f;
#pragma unroll
      for (int r=0;r<4;r++) {
        int rowg = row0 + wm*64 + i*16 + quad*4 + r;
        f16 val = (f16)(acc[i][j][r] + bias);
        if (z == 2) {
          int bb = rowg >> 11, ss = rowg & (S_-1);
          vT[((size_t)bb*D_ + colg)*S_ + ss] = val;
        } else {
          out[(size_t)rowg*D_ + colg] = val;
        }
      }
    }
  }
}

// ---------------- flash attention (coalesced-q + k-pair double buffer) ----------------
// Structure per ko (two barriers, NEITHER exposes memory latency):
//   barrier A : drains k-DMA issued one full MFMA phase (~2500 cyc) earlier (free)
//               + q ds_writes from previous iteration tail (lgkm, ~free)
//   issue DMA for next ko's k pair into the idle buffer pair
//   issue COALESCED global loads of next ko's q slice into registers
//   MFMA phase (64 MFMA/wave) reading k[cur] + q_lds
//   barrier B : orders q_lds reuse (all waves done reading)
//   mix-multiply + swizzled ds_write of next q slice
// LDS: k[4][8KB] dbuf pairs (64KB) + q slice (16KB, xor-swizzled) = 80KB exactly
//      -> 2 blocks/CU.  P (34.8KB) aliases k[0..2]; red_l aliases q.
#define TQ 128
#define TK 128
#define LDP 136

__global__ __launch_bounds__(256, 2) void attn_kernel(
    const f16* __restrict__ q16, const f16* __restrict__ k16,
    const f16* __restrict__ vT, const f16* __restrict__ mix16,
    float* __restrict__ out)
{
  const int b = blockIdx.z;
  const int h = blockIdx.y;
  const int s0 = blockIdx.x * TQ;
  const int tid = threadIdx.x;
  const int lane = tid & 63, wid = tid >> 6;
  const int wm = wid >> 1, wn = wid & 1;
  const int quad = lane >> 4, l16 = lane & 15;

  __shared__ __align__(16) union {
    struct { f16 k[4][TK*BK]; f16 q[TQ*BK]; } s;           // 65536 + 16384 = 81920 B
    struct { f16 P[TQ][LDP]; } p;                          // 34816 B (aliases k[0..2])
    struct { f16 _pad[4*TK*BK]; float red_l[2][TQ]; } r;   // red_l aliases q
  } u;

  float l_lane[16];
#pragma unroll
  for (int t=0;t<16;t++) l_lane[t] = 0.0f;

  float4_ o_acc[4][2];
#pragma unroll
  for (int i=0;i<4;i++)
#pragma unroll
    for (int j=0;j<2;j++) o_acc[i][j] = (float4_)0.0f;

  const f16* qbase = q16 + (size_t)(b*S_ + s0)*D_;
  const f16* kbase = k16 + (size_t)b*S_*D_;
  const f16* mrow  = mix16 + h*D_;
  const f16* vTb   = vT + (size_t)(b*D_ + h*HD_)*S_;

  // stage k-tile pair p (tiles u.s.k[2p], u.s.k[2p+1]) for (t0g, ko_): 8 DMA/thread
#define STAGE_PAIR(p, t0g, ko_) do {                                         \
    const f16* k0g_ = kbase + (size_t)(t0g)*D_ + (ko_);                      \
    const f16* k1g_ = k0g_ + (size_t)TK*D_;                                  \
    _Pragma("unroll")                                                        \
    for (int c_=0; c_<4; c_++) {                                             \
      int slot_ = (wid*4+c_)*64 + lane;                                      \
      int r_ = slot_ >> 3;                                                   \
      int gc_ = (slot_ & 7) ^ (r_ & 7);                                      \
      gl_lds16(k0g_ + (size_t)r_*D_ + gc_*8, u.s.k[2*(p)]   + (size_t)(wid*4+c_)*64*8); \
      gl_lds16(k1g_ + (size_t)r_*D_ + gc_*8, u.s.k[2*(p)+1] + (size_t)(wid*4+c_)*64*8); \
    } } while (0)

  // coalesced q staging (thread -> 4 chunks; 8 threads cover one 128B row slice)
#define QLOAD(ko_) do {                                                      \
    _Pragma("unroll")                                                        \
    for (int it_=0; it_<4; it_++) {                                          \
      int c_ = it_*256 + tid; int r_ = c_>>3; int cc_ = c_&7;                \
      qv[it_] = *(const half8*)&qbase[(size_t)r_*D_ + (ko_) + cc_*8];        \
      mv[it_] = *(const half8*)&mrow[(ko_) + cc_*8];                         \
    } } while (0)
#define QWRITE() do {                                                        \
    _Pragma("unroll")                                                        \
    for (int it_=0; it_<4; it_++) {                                          \
      int c_ = it_*256 + tid; int r_ = c_>>3; int cc_ = c_&7;                \
      *(half8*)&u.s.q[(size_t)(((r_<<3) | (cc_ ^ (r_&7))) << 3)] = qv[it_]*mv[it_]; \
    } } while (0)

  STAGE_PAIR(0, 0, 0);   // prologue DMA for t0=0

  for (int t0 = 0; t0 < S_; t0 += 2*TK) {
    // prologue q staging for ko=0 (DMA pair0 in flight; drained at first barrier A)
    half8 qv[4], mv[4];
    QLOAD(0);
    QWRITE();

    float4_ sacc[2][4][4];
#pragma unroll
    for (int tt=0;tt<2;tt++)
#pragma unroll
      for (int i=0;i<4;i++)
#pragma unroll
        for (int j=0;j<4;j++) sacc[tt][i][j] = (float4_)0.0f;

#pragma unroll 2
    for (int ko_i = 0; ko_i < D_/BK; ko_i++) {
      const int ko = ko_i * BK;
      const int cur = ko_i & 1;
      __syncthreads();   // A: drains phase-old DMA(k[cur]) + prev q ds_writes
      if (ko_i < D_/BK - 1) {
        STAGE_PAIR(cur^1, t0, ko + BK);   // next ko's k pair -> idle buffers
        QLOAD(ko + BK);                   // next ko's q slice -> regs (coalesced)
      }

      __builtin_amdgcn_s_setprio(1);
#pragma unroll
      for (int kk2=0; kk2<2; kk2++) {
        half8 a[4];
#pragma unroll
        for (int i=0;i<4;i++) {
          int rr = wm*64 + i*16 + l16;
          int ck = kk2*4 + quad;
          a[i] = *(const half8*)&u.s.q[(size_t)(((rr<<3) | (ck ^ (rr&7))) << 3)];
        }
#pragma unroll
        for (int tt=0;tt<2;tt++) {
          const f16* kb = u.s.k[2*cur + tt];
          half8 bf[4];
#pragma unroll
          for (int j=0;j<4;j++) {
            int rr = wn*64 + j*16 + l16;
            int ck = kk2*4 + quad;
            bf[j] = *(const half8*)&kb[(size_t)(((rr<<3) | (ck ^ (rr&7))) << 3)];
          }
#pragma unroll
          for (int i=0;i<4;i++)
#pragma unroll
            for (int j=0;j<4;j++)
              sacc[tt][i][j] = __builtin_amdgcn_mfma_f32_16x16x32_f16(a[i], bf[j], sacc[tt][i][j], 0,0,0);
        }
      }
      __builtin_amdgcn_s_setprio(0);

      __syncthreads();   // B: all q_lds reads done -> safe to overwrite
      if (ko_i < D_/BK - 1) QWRITE();
    }
    // after barrier B of last ko: all k/q reads done; P may overwrite k region

    // ---- per sub-tile: P = exp2(S), l partials, P->LDS, PV ----
#pragma unroll
    for (int tt=0;tt<2;tt++) {
#pragma unroll
      for (int i=0;i<4;i++)
#pragma unroll
        for (int j=0;j<4;j++)
#pragma unroll
          for (int r=0;r<4;r++) {
            float p = __builtin_exp2f(sacc[tt][i][j][r]);
            l_lane[i*4+r] += p;
            u.p.P[wm*64+i*16+quad*4+r][wn*64+j*16+l16] = (f16)p;
          }

      // prefetch PV B-fragments (latency hides under barrier)
      half8 vb[8];
#pragma unroll
      for (int ki=0; ki<4; ki++)
#pragma unroll
        for (int j=0; j<2; j++) {
          int ch = wn*32 + j*16 + l16;
          vb[ki*2+j] = *(const half8*)&vTb[(size_t)ch*S_ + t0 + tt*TK + ki*32 + quad*8];
        }

      __syncthreads();

      __builtin_amdgcn_s_setprio(1);
#pragma unroll
      for (int ki=0; ki<4; ki++) {
        half8 pa[4];
#pragma unroll
        for (int i=0;i<4;i++) pa[i] = *(const half8*)&u.p.P[wm*64+i*16+l16][ki*32+quad*8];
#pragma unroll
        for (int i=0;i<4;i++)
#pragma unroll
          for (int j=0;j<2;j++)
            o_acc[i][j] = __builtin_amdgcn_mfma_f32_16x16x32_f16(pa[i], vb[ki*2+j], o_acc[i][j], 0,0,0);
      }
      __builtin_amdgcn_s_setprio(0);
      __syncthreads();
    }

    // prologue DMA for the next t0 (P reads complete; pair0 region dead)
    if (t0 + 2*TK < S_) STAGE_PAIR(0, t0 + 2*TK, 0);
  }

  // ---- epilogue: single l reduction (butterfly over l16, cross-wave via LDS) ----
#pragma unroll
  for (int d=1; d<16; d<<=1)
#pragma unroll
    for (int t=0;t<16;t++) l_lane[t] += __shfl_xor(l_lane[t], d);
  if (l16 == 0) {
#pragma unroll
    for (int i=0;i<4;i++)
#pragma unroll
      for (int r=0;r<4;r++)
        u.r.red_l[wn][wm*64+i*16+quad*4+r] = l_lane[i*4+r];
  }
  __syncthreads();

#pragma unroll
  for (int i=0;i<4;i++) {
#pragma unroll
    for (int r=0;r<4;r++) {
      int row = wm*64 + i*16 + quad*4 + r;
      float linv = 1.0f / (u.r.red_l[0][row] + u.r.red_l[1][row]);
#pragma unroll
      for (int j=0;j<2;j++) {
        int colg = h*HD_ + wn*32 + j*16 + l16;
        out[(size_t)(b*S_ + s0 + row)*D_ + colg] = o_acc[i][j][r] * linv;
      }
    }
  }
}

// ---------------- launch ----------------
extern "C" void kernel_launch(void* const* d_in, const int* in_sizes, int n_in,
                              void* d_out, int out_size, void* d_ws, size_t ws_size,
                              hipStream_t stream) {
  (void)in_sizes; (void)n_in; (void)out_size; (void)ws_size;
  const float* hs  = (const float*)d_in[0];
  const float* Wq  = (const float*)d_in[1];
  const float* Wk  = (const float*)d_in[2];
  const float* Wv  = (const float*)d_in[3];
  const float* bv  = (const float*)d_in[4];
  const float* mix = (const float*)d_in[5];
  float* out = (float*)d_out;

  char* ws = (char*)d_ws;
  f16* hs16  = (f16*)(ws);                       // 8 MB
  f16* w16   = (f16*)(ws + 8388608);             // 6 MB
  f16* mix16 = (f16*)(ws + 14680064);            // 32 KB
  f16* q16   = (f16*)(ws + 14712832);            // 8 MB
  f16* k16   = (f16*)(ws + 23101440);            // 8 MB
  f16* vT    = (f16*)(ws + 31490048);            // 8 MB

  convert_kernel<<<2048, 256, 0, stream>>>(hs, Wq, Wk, Wv, mix,
                                           hs16, w16, w16+N_W, w16+2*N_W, mix16);
  qkv_kernel<<<dim3(D_/BN, (B_*S_)/BM, 3), 256, 0, stream>>>(
      hs16, w16, bv, q16, k16, vT);
  attn_kernel<<<dim3(S_/TQ, H_, B_), 256, 0, stream>>>(
      q16, k16, vT, mix16, out);
}